// Round 8
// baseline (810.865 us; speedup 1.0000x reference)
//
#include <hip/hip_runtime.h>

// OptimizedLinear: out = x@W^T + bias - lr[:,None]*(x@G^T + bias_grad)
// B=4096, IN=OUT=2048, fp32 in/out. bf16 MFMA fused dual-accumulator GEMM.
//
// Round 8: split-K=2, BK=32, 128x128 tile, conflict-free XOR swizzle
// (R7-proven, adapted to 64 super-rows x 128B), 24KB LDS -> 4 blocks/CU.
// R7 accounting: MFMA 2483 + ds_read 2304 + staging 380 cyc per CU-step-pair
// are SERIALIZED (in-phase barriers of 2 co-resident blocks). 4 independent
// blocks/CU decorrelate phases so the MFMA and LDS pipes overlap.
// Halves merge via native fp32 unsafeAtomicAdd; out zeroed by cvt kernel.
//
// Lessons carried: SQ_LDS_BANK_CONFLICT is REAL read-conflict cost (R7: XOR
// swizzle 6.29M -> 0, -12.5us) — revised from the R2-era "artifact" claim.
// Scattered per-wave A-loads poison the drain (R6). 256-reg acc spills (R5,
// tripwire WRITE_SIZE >> expected). Cooperative launch no-ops (R3). Smaller
// tiles raise staged bytes/FLOP (R4). MFMA floor ~33us; harness+cvt ~95us.

typedef unsigned short ushort_t;
typedef __attribute__((ext_vector_type(8))) short short8;       // 8 bf16 = 4 VGPR
typedef __attribute__((ext_vector_type(8))) unsigned short ushort8;
typedef __attribute__((ext_vector_type(4))) float f32x4;

#define GPTR(p) ((const __attribute__((address_space(1))) void*)(p))
#define LPTR(p) ((__attribute__((address_space(3))) void*)(p))

static constexpr int Kdim  = 2048;
static constexpr int Ndim  = 2048;
static constexpr int KHALF = 1024;   // split-K=2
static constexpr int BK    = 32;

__device__ __forceinline__ unsigned short f2bf(float f) {
    union { float f; unsigned u; } c; c.f = f;
    unsigned u = c.u;
    unsigned r = (u + 0x7fffu + ((u >> 16) & 1u)) >> 16;  // RNE
    return (unsigned short)r;
}

// Converts x (uX ushort8-units), W (uW), G (uW), then ZEROES out (uZ f32x8
// units) — ordering vs GEMM guaranteed by same-stream serialization.
__global__ void cvt_zero_kernel(const float* __restrict__ x,
                                const float* __restrict__ W,
                                const float* __restrict__ G,
                                ushort_t* __restrict__ xb,
                                ushort_t* __restrict__ wb,
                                ushort_t* __restrict__ gb,
                                float* __restrict__ out,
                                int uX, int uW, int uZbase) {
    int u = blockIdx.x * blockDim.x + threadIdx.x;
    if (u >= uZbase) {                       // zero-init range for out
        int i = (u - uZbase) * 8;
        float4 z = {0.f, 0.f, 0.f, 0.f};
        *(float4*)(out + i)     = z;
        *(float4*)(out + i + 4) = z;
        return;
    }
    const float* src; ushort_t* dst;
    if (u < uX)            { src = x; dst = xb; }
    else if (u < uX + uW)  { src = W; dst = wb; u -= uX; }
    else                   { src = G; dst = gb; u -= uX + uW; }
    int i = u * 8;
    float4 a = *(const float4*)(src + i);
    float4 b = *(const float4*)(src + i + 4);
    ushort8 r;
    r[0] = f2bf(a.x); r[1] = f2bf(a.y); r[2] = f2bf(a.z); r[3] = f2bf(a.w);
    r[4] = f2bf(b.x); r[5] = f2bf(b.y); r[6] = f2bf(b.z); r[7] = f2bf(b.w);
    *(ushort8*)(dst + i) = r;
}

// ---- fused dual GEMM, 128x128 tile, BK=32, split-K=2 ----
// 256 threads = 4 waves (2x2), each wave 64x64 = 4x4 MFMA tiles, dual acc.
// LDS tile = 64 super-rows (2 elem-rows) x 8 granule-slots x 16B = 8KB.
// Slot (R, j) holds granule g' = j ^ (R&7), where g' encodes
// (elem-row = 2R + (g'>>2), k-granule = g'&3). Swizzle applied on the GLOBAL
// fetch (LDS dst is HW-forced to base + lane*16). Fragment b128 reads hit
// each 16B bank-group exactly 8x -> conflict-free minimum (verified R7-style).
__global__ __launch_bounds__(256, 4) void fused_gemm_kernel(
    const ushort_t* __restrict__ xb,   // [4096, 2048] bf16
    const ushort_t* __restrict__ wb,   // [2048, 2048] bf16
    const ushort_t* __restrict__ gb,   // [2048, 2048] bf16
    const float* __restrict__ bias,    // [2048]
    const float* __restrict__ bgrad,   // [2048]
    const float* __restrict__ lr,      // [4096]
    float* __restrict__ out)           // [4096, 2048] fp32 (pre-zeroed)
{
    __shared__ ushort_t As[128 * BK];  // 8 KB
    __shared__ ushort_t Ws[128 * BK];  // 8 KB
    __shared__ ushort_t Gs[128 * BK];  // 8 KB

    const int t    = threadIdx.x;
    const int wave = t >> 6;
    const int lane = t & 63;
    const int wm   = (wave >> 1) * 64;
    const int wn   = (wave & 1) * 64;
    const int bx   = blockIdx.x;   // N tile (0..15)
    const int by   = blockIdx.y;   // M tile (0..31)
    const int h    = blockIdx.z;   // K half (0..1)

    const int fr   = lane & 15;    // fragment row
    const int quad = lane >> 4;    // k-granule select (0..3)

    f32x4 accB[4][4] = {};
    f32x4 accP[4][4] = {};

    // --- staging addressing: 2 issues x 256 threads cover 512 slots ---
    int rowI[2], kkI[2];
#pragma unroll
    for (int i = 0; i < 2; ++i) {
        int s  = i * 256 + t;
        int R  = s >> 3;
        int gp = (s & 7) ^ (R & 7);
        rowI[i] = 2 * R + (gp >> 2);
        kkI[i]  = (gp & 3) * 8;
    }

    const size_t aBase = (size_t)(by * 128);
    const size_t wBase = (size_t)(bx * 128);

    const ushort_t* gA[2]; const ushort_t* gW[2]; const ushort_t* gG[2];
    ushort_t* lA[2]; ushort_t* lW[2]; ushort_t* lG[2];
#pragma unroll
    for (int i = 0; i < 2; ++i) {
        gA[i] = xb + (aBase + rowI[i]) * Kdim + kkI[i];
        gW[i] = wb + (wBase + rowI[i]) * Kdim + kkI[i];
        gG[i] = gb + (wBase + rowI[i]) * Kdim + kkI[i];
        const int dst = (i * 256 + wave * 64) * 8;   // wave-uniform + lane*16B
        lA[i] = As + dst; lW[i] = Ws + dst; lG[i] = Gs + dst;
    }

    // fragment LDS offsets (ushort index): r = rowbase+fr, R=r>>1,
    // j = ((r&1)*4 + quad) ^ (R&7), idx = R*64 + j*8
    int offA[4], offWG[4];
#pragma unroll
    for (int mt = 0; mt < 4; ++mt) {
        {
            int r = wm + mt * 16 + fr, R = r >> 1;
            int j = (((r & 1) * 4 + quad) ^ (R & 7));
            offA[mt] = R * 64 + j * 8;
        }
        {
            int r = wn + mt * 16 + fr, R = r >> 1;
            int j = (((r & 1) * 4 + quad) ^ (R & 7));
            offWG[mt] = R * 64 + j * 8;
        }
    }

    const int kEnd = h * KHALF + KHALF;
    for (int k0 = h * KHALF; k0 < kEnd; k0 += BK) {
#pragma unroll
        for (int i = 0; i < 2; ++i) {
            __builtin_amdgcn_global_load_lds(GPTR(gA[i] + k0), LPTR(lA[i]), 16, 0, 0);
            __builtin_amdgcn_global_load_lds(GPTR(gW[i] + k0), LPTR(lW[i]), 16, 0, 0);
            __builtin_amdgcn_global_load_lds(GPTR(gG[i] + k0), LPTR(lG[i]), 16, 0, 0);
        }
        __syncthreads();

        short8 af[4], wf[4], gf[4];
#pragma unroll
        for (int mt = 0; mt < 4; ++mt) {
            af[mt] = *(const short8*)(As + offA[mt]);
            wf[mt] = *(const short8*)(Ws + offWG[mt]);
            gf[mt] = *(const short8*)(Gs + offWG[mt]);
        }
#pragma unroll
        for (int mt = 0; mt < 4; ++mt)
#pragma unroll
            for (int nt = 0; nt < 4; ++nt) {
                accB[mt][nt] = __builtin_amdgcn_mfma_f32_16x16x32_bf16(
                    af[mt], wf[nt], accB[mt][nt], 0, 0, 0);
                accP[mt][nt] = __builtin_amdgcn_mfma_f32_16x16x32_bf16(
                    af[mt], gf[nt], accP[mt][nt], 0, 0, 0);
            }
        __syncthreads();
    }

    // --- epilogue: atomic-add this half's contribution ---
    // out += accB - lr[m]*accP, plus (bias[n] - lr[m]*bgrad[n]) from half 0.
    // C/D layout: col = lane&15, row = quad*4 + reg
    const int col = fr;
    const int gmb = by * 128 + wm;
    const int gnb = bx * 128 + wn;
    const bool addBias = (h == 0);

    float lrv[4][4];
#pragma unroll
    for (int mt = 0; mt < 4; ++mt)
#pragma unroll
        for (int i = 0; i < 4; ++i)
            lrv[mt][i] = lr[gmb + mt * 16 + quad * 4 + i];

#pragma unroll
    for (int nt = 0; nt < 4; ++nt) {
        const int gn = gnb + nt * 16 + col;
        const float bn = addBias ? bias[gn]  : 0.f;
        const float bg = addBias ? bgrad[gn] : 0.f;
#pragma unroll
        for (int mt = 0; mt < 4; ++mt) {
#pragma unroll
            for (int i = 0; i < 4; ++i) {
                const int gm = gmb + mt * 16 + quad * 4 + i;
                float v = accB[mt][nt][i] + bn - lrv[mt][i] * (accP[mt][nt][i] + bg);
                unsafeAtomicAdd(out + (size_t)gm * Ndim + gn, v);
            }
        }
    }
}

extern "C" void kernel_launch(void* const* d_in, const int* in_sizes, int n_in,
                              void* d_out, int out_size, void* d_ws, size_t ws_size,
                              hipStream_t stream) {
    const float* x     = (const float*)d_in[0];  // [4096, 2048]
    const float* W     = (const float*)d_in[1];  // [2048, 2048]
    const float* bias  = (const float*)d_in[2];  // [2048]
    const float* G     = (const float*)d_in[3];  // [2048, 2048]
    const float* bgrad = (const float*)d_in[4];  // [2048]
    const float* lr    = (const float*)d_in[5];  // [4096]
    float* out = (float*)d_out;

    const int nX = 4096 * 2048;
    const int nW = 2048 * 2048;

    ushort_t* xb = (ushort_t*)d_ws;
    ushort_t* wb = xb + nX;
    ushort_t* gb = wb + nW;

    const int uX = nX / 8, uW = nW / 8;
    const int uZbase = uX + 2 * uW;               // 2,097,152
    const int uZ = (4096 * 2048) / 8;             // 1,048,576 zero-units
    const int totalU = uZbase + uZ;               // 3,145,728
    cvt_zero_kernel<<<totalU / 256, 256, 0, stream>>>(x, W, G, xb, wb, gb, out,
                                                      uX, uW, uZbase);

    dim3 grid(16, 32, 2);  // N x M x K-half = 1024 blocks = 4/CU resident
    fused_gemm_kernel<<<grid, 256, 0, stream>>>(xb, wb, gb, bias, bgrad, lr, out);
}

// Round 9
// 184.226 us; speedup vs baseline: 4.4015x; 4.4015x over previous
//
#include <hip/hip_runtime.h>

// OptimizedLinear: out = x@W^T + bias - lr[:,None]*(x@G^T + bias_grad)
// B=4096, IN=OUT=2048, fp32 in/out. bf16 MFMA fused dual-accumulator GEMM.
//
// Round 9: A bypasses LDS. cvt writes x in MFMA-fragment-contiguous order
// xb_t[Mt][Kt][lane][8] so each A-fragment load is ONE coalesced 1KB
// global_load_dwordx4 (block-uniform + lane*16B) — fixes R6's scattered-load
// poison. W/G keep the R7-proven BK=64 LDS path (XOR-8 swizzle, 0 conflicts,
// 2-barrier K-loop). Removes 1/3 of ds_reads and staging from the serialized
// LDS pipe: model 5310 -> ~4450 cyc/CU-step-pair.
//
// Lessons carried: dense global atomics are catastrophic (R8: 3.5GB HBM,
// 700us). SQ_LDS_BANK_CONFLICT is real read-conflict cost; XOR-8 over 128B
// rows kills it (R7). Scattered per-wave A-loads poison the drain (R6) —
// hence the fragment-contiguous transpose. >=240 live VGPRs spill (R5;
// tripwire WRITE_SIZE >> 40MB). Cooperative launch no-ops (R3). Smaller
// tiles raise staged bytes/FLOP (R4). MFMA floor ~33us; harness+cvt ~95us.

typedef unsigned short ushort_t;
typedef __attribute__((ext_vector_type(8))) short short8;       // 8 bf16 = 4 VGPR
typedef __attribute__((ext_vector_type(8))) unsigned short ushort8;
typedef __attribute__((ext_vector_type(4))) float f32x4;

#define GPTR(p) ((const __attribute__((address_space(1))) void*)(p))
#define LPTR(p) ((__attribute__((address_space(3))) void*)(p))

static constexpr int Kdim = 2048;
static constexpr int Ndim = 2048;
static constexpr int BK   = 64;

__device__ __forceinline__ unsigned short f2bf(float f) {
    union { float f; unsigned u; } c; c.f = f;
    unsigned u = c.u;
    unsigned r = (u + 0x7fffu + ((u >> 16) & 1u)) >> 16;  // RNE
    return (unsigned short)r;
}

// Converts x into fragment-contiguous layout xb_t (uXg granule-units), and
// W, G into row-major bf16 (uW units each). Unit = 8 elems = one 16B granule.
//
// xb_t granule d: lane=d&63 (fr=lane&15, quad=lane>>4), Kt=(d>>6)&63,
// Mt=d>>12; holds x[Mt*16+fr][Kt*32+quad*8 .. +8]. Writes perfectly
// coalesced (consecutive d -> consecutive 16B); reads are 128B chunks.
__global__ void cvt_all_kernel(const float* __restrict__ x,
                               const float* __restrict__ W,
                               const float* __restrict__ G,
                               ushort_t* __restrict__ xt,
                               ushort_t* __restrict__ wb,
                               ushort_t* __restrict__ gb,
                               int uXg, int uW) {
    int u = blockIdx.x * blockDim.x + threadIdx.x;
    const float* src;
    ushort_t* dstp;
    if (u < uXg) {
        const int lane = u & 63;
        const int Kt   = (u >> 6) & 63;
        const int Mt   = u >> 12;
        const int fr   = lane & 15;
        const int quad = lane >> 4;
        src  = x + (size_t)(Mt * 16 + fr) * Kdim + Kt * 32 + quad * 8;
        dstp = xt + (size_t)u * 8;
    } else if (u < uXg + uW) {
        int v = u - uXg;
        src  = W + (size_t)v * 8;
        dstp = wb + (size_t)v * 8;
    } else {
        int v = u - uXg - uW;
        src  = G + (size_t)v * 8;
        dstp = gb + (size_t)v * 8;
    }
    float4 a = *(const float4*)(src);
    float4 b = *(const float4*)(src + 4);
    ushort8 r;
    r[0] = f2bf(a.x); r[1] = f2bf(a.y); r[2] = f2bf(a.z); r[3] = f2bf(a.w);
    r[4] = f2bf(b.x); r[5] = f2bf(b.y); r[6] = f2bf(b.z); r[7] = f2bf(b.w);
    *(ushort8*)(dstp) = r;
}

// ---- fused dual GEMM, 128x128 tile, BK=64, A direct-from-global ----
// 256 threads = 4 waves (2x2), each wave 64x64 = 4x4 MFMA tiles, dual acc.
// W/G LDS tile: 128 rows x 64 k (128B/row), slot (r, j) holds granule
// j ^ (r&7) — XOR-8 swizzle on the GLOBAL fetch; fragment b128 reads hit
// each bank-group exactly 8x (conflict-free, R7-verified).
// A fragment for (wave m-tile mt, K32-tile Kt): one coalesced dwordx4 at
// xt + ((Mt*64 + Kt)*64 + lane)*8.
__global__ __launch_bounds__(256, 2) void fused_gemm_kernel(
    const ushort_t* __restrict__ xt,   // fragment-contiguous x, 16 MB
    const ushort_t* __restrict__ wb,   // [2048, 2048] bf16
    const ushort_t* __restrict__ gb,   // [2048, 2048] bf16
    const float* __restrict__ bias,    // [2048]
    const float* __restrict__ bgrad,   // [2048]
    const float* __restrict__ lr,      // [4096]
    float* __restrict__ out)           // [4096, 2048] fp32
{
    __shared__ ushort_t Ws[128 * BK];  // 16 KB
    __shared__ ushort_t Gs[128 * BK];  // 16 KB

    const int t    = threadIdx.x;
    const int wave = t >> 6;
    const int lane = t & 63;
    const int wm   = (wave >> 1) * 64;
    const int wn   = (wave & 1) * 64;
    const int bx   = blockIdx.x;   // N tile (0..15)
    const int by   = blockIdx.y;   // M tile (0..31)

    const int fr   = lane & 15;    // fragment row
    const int quad = lane >> 4;    // k-granule select (0..3)

    f32x4 accB[4][4] = {};
    f32x4 accP[4][4] = {};

    // --- W/G staging: 4 issues x 256 threads cover 1024 slots each ---
    int rowI[4], kkI[4];
#pragma unroll
    for (int i = 0; i < 4; ++i) {
        int s = i * 256 + t;
        rowI[i] = s >> 3;
        kkI[i]  = (((s & 7) ^ (rowI[i] & 7)) * 8);
    }

    const size_t wBase = (size_t)(bx * 128);
    const ushort_t* gW[4]; const ushort_t* gG[4];
    ushort_t* lW[4]; ushort_t* lG[4];
#pragma unroll
    for (int i = 0; i < 4; ++i) {
        gW[i] = wb + (wBase + rowI[i]) * Kdim + kkI[i];
        gG[i] = gb + (wBase + rowI[i]) * Kdim + kkI[i];
        const int dst = (i * 256 + wave * 64) * 8;   // wave-uniform + lane*16B
        lW[i] = Ws + dst; lG[i] = Gs + dst;
    }

    // --- A fragment base: Mt row of this wave, granule = lane ---
    const int MtBase = by * 8 + (wave >> 1) * 4;     // 4 m-tiles (16 rows each)
    const ushort_t* pa = xt + (((size_t)MtBase * 64) * 64 + lane) * 8;
    // af for (mt, Kt): pa + (mt*64*64 + Kt*64)*8

    for (int k0 = 0; k0 < Kdim; k0 += BK) {
#pragma unroll
        for (int i = 0; i < 4; ++i) {
            __builtin_amdgcn_global_load_lds(GPTR(gW[i] + k0), LPTR(lW[i]), 16, 0, 0);
            __builtin_amdgcn_global_load_lds(GPTR(gG[i] + k0), LPTR(lG[i]), 16, 0, 0);
        }
        __syncthreads();

        const int KtBase = k0 >> 5;
#pragma unroll
        for (int j = 0; j < 2; ++j) {
            const int kc = (((j * 4 + quad) ^ (fr & 7)) * 8);
            short8 af[4], wf[4], gf[4];
#pragma unroll
            for (int mt = 0; mt < 4; ++mt)
                af[mt] = *(const short8*)(pa + ((size_t)mt * 64 + (KtBase + j)) * 64 * 8);
#pragma unroll
            for (int nt = 0; nt < 4; ++nt) {
                wf[nt] = *(const short8*)(Ws + (wn + nt * 16 + fr) * BK + kc);
                gf[nt] = *(const short8*)(Gs + (wn + nt * 16 + fr) * BK + kc);
            }
#pragma unroll
            for (int mt = 0; mt < 4; ++mt)
#pragma unroll
                for (int nt = 0; nt < 4; ++nt) {
                    accB[mt][nt] = __builtin_amdgcn_mfma_f32_16x16x32_bf16(
                        af[mt], wf[nt], accB[mt][nt], 0, 0, 0);
                    accP[mt][nt] = __builtin_amdgcn_mfma_f32_16x16x32_bf16(
                        af[mt], gf[nt], accP[mt][nt], 0, 0, 0);
                }
        }
        __syncthreads();
    }

    // --- epilogue: out = base + bias[n] - lr[m]*(pert + bgrad[n]) ---
    // C/D layout: col = lane&15, row = quad*4 + reg
    const int col = fr;
    const int gmb = by * 128 + wm;
    const int gnb = bx * 128 + wn;

    float lrv[4][4];
#pragma unroll
    for (int mt = 0; mt < 4; ++mt)
#pragma unroll
        for (int i = 0; i < 4; ++i)
            lrv[mt][i] = lr[gmb + mt * 16 + quad * 4 + i];

#pragma unroll
    for (int nt = 0; nt < 4; ++nt) {
        const int gn = gnb + nt * 16 + col;
        const float bn = bias[gn];
        const float bg = bgrad[gn];
#pragma unroll
        for (int mt = 0; mt < 4; ++mt) {
#pragma unroll
            for (int i = 0; i < 4; ++i) {
                const int gm = gmb + mt * 16 + quad * 4 + i;
                float v = accB[mt][nt][i] + bn - lrv[mt][i] * (accP[mt][nt][i] + bg);
                __builtin_nontemporal_store(v, out + (size_t)gm * Ndim + gn);
            }
        }
    }
}

extern "C" void kernel_launch(void* const* d_in, const int* in_sizes, int n_in,
                              void* d_out, int out_size, void* d_ws, size_t ws_size,
                              hipStream_t stream) {
    const float* x     = (const float*)d_in[0];  // [4096, 2048]
    const float* W     = (const float*)d_in[1];  // [2048, 2048]
    const float* bias  = (const float*)d_in[2];  // [2048]
    const float* G     = (const float*)d_in[3];  // [2048, 2048]
    const float* bgrad = (const float*)d_in[4];  // [2048]
    const float* lr    = (const float*)d_in[5];  // [4096]
    float* out = (float*)d_out;

    const int nX = 4096 * 2048;
    const int nW = 2048 * 2048;

    ushort_t* xt = (ushort_t*)d_ws;   // 16 MB fragment-contiguous
    ushort_t* wb = xt + nX;
    ushort_t* gb = wb + nW;

    const int uXg = nX / 8, uW = nW / 8;
    const int totalU = uXg + 2 * uW;              // 2,097,152
    cvt_all_kernel<<<totalU / 256, 256, 0, stream>>>(x, W, G, xt, wb, gb, uXg, uW);

    dim3 grid(16, 32);   // N tiles x M tiles = 512 blocks = 2/CU
    fused_gemm_kernel<<<grid, 256, 0, stream>>>(xt, wb, gb, bias, bgrad, lr, out);
}